// Round 1
// baseline (30.583 us; speedup 1.0000x reference)
//
#include <hip/hip_runtime.h>
#include <hip/hip_bf16.h>

// PSRoIAlign: features [B, C=D*G*G, H, W] fp32, rois [N,5] (b, x1,y1,x2,y2 in
// image coords), output [N, D, G, G] fp32. G=7, SR=2, D=10 for this problem.

#define G 7
#define SR 2
#define D_OUT 10

__global__ void psroi_align_kernel(const float* __restrict__ rois,
                                   const float* __restrict__ feat,
                                   const int* __restrict__ stride_p,
                                   int N, int B, int C, int H, int W,
                                   float* __restrict__ out) {
    int idx = blockIdx.x * blockDim.x + threadIdx.x;
    int total = N * D_OUT * G * G;
    if (idx >= total) return;

    // stride may arrive as int32 or float32 bits; disambiguate.
    int iv = stride_p[0];
    float stride_f;
    if (iv > 0 && iv <= 65536) stride_f = (float)iv;
    else                       stride_f = __int_as_float(iv);
    float spatial_scale = 1.0f / stride_f;

    int pw = idx % G;
    int ph = (idx / G) % G;
    int d  = (idx / (G * G)) % D_OUT;
    int n  = idx / (G * G * D_OUT);

    const float* roi = rois + (size_t)n * 5;
    int   b  = (int)roi[0];
    float sw = roi[1] * spatial_scale - 0.5f;
    float sh = roi[2] * spatial_scale - 0.5f;
    float ew = roi[3] * spatial_scale - 0.5f;
    float eh = roi[4] * spatial_scale - 0.5f;
    float roi_w = fmaxf(ew - sw, 0.1f);
    float roi_h = fmaxf(eh - sh, 0.1f);
    float bin_h = roi_h / (float)G;
    float bin_w = roi_w / (float)G;

    // position-sensitive channel: c = (d*G + ph)*G + pw
    int c = (d * G + ph) * G + pw;
    const float* __restrict__ fplane = feat + ((size_t)b * C + c) * (size_t)(H * W);

    float acc = 0.0f;
#pragma unroll
    for (int iy = 0; iy < SR; ++iy) {
        float y  = sh + ((float)ph + ((float)iy + 0.5f) / (float)SR) * bin_h;
        bool  vy = (y > -1.0f) && (y < (float)H);
        float cy = fmaxf(y, 0.0f);
        int  ylo = min((int)floorf(cy), H - 1);
        int  yhi = min(ylo + 1, H - 1);
        float ly = (ylo >= H - 1) ? 0.0f : (cy - (float)ylo);
        float hy = 1.0f - ly;
#pragma unroll
        for (int ix = 0; ix < SR; ++ix) {
            float x  = sw + ((float)pw + ((float)ix + 0.5f) / (float)SR) * bin_w;
            bool  vx = (x > -1.0f) && (x < (float)W);
            float cx = fmaxf(x, 0.0f);
            int  xlo = min((int)floorf(cx), W - 1);
            int  xhi = min(xlo + 1, W - 1);
            float lx = (xlo >= W - 1) ? 0.0f : (cx - (float)xlo);
            float hx = 1.0f - lx;
            if (vy && vx) {
                float v00 = fplane[(size_t)ylo * W + xlo];
                float v01 = fplane[(size_t)ylo * W + xhi];
                float v10 = fplane[(size_t)yhi * W + xlo];
                float v11 = fplane[(size_t)yhi * W + xhi];
                acc += hy * hx * v00 + hy * lx * v01 + ly * hx * v10 + ly * lx * v11;
            }
        }
    }
    out[idx] = acc * (1.0f / (float)(SR * SR));
}

extern "C" void kernel_launch(void* const* d_in, const int* in_sizes, int n_in,
                              void* d_out, int out_size, void* d_ws, size_t ws_size,
                              hipStream_t stream) {
    const float* rois = (const float*)d_in[0];
    const float* feat = (const float*)d_in[1];
    const int*   strd = (const int*)d_in[2];
    float* out = (float*)d_out;

    int N = in_sizes[0] / 5;
    const int C = D_OUT * G * G;   // 490
    const int H = 160, W = 160;
    int B = in_sizes[1] / (C * H * W);

    int total = N * D_OUT * G * G;
    int block = 256;
    int grid = (total + block - 1) / block;
    psroi_align_kernel<<<grid, block, 0, stream>>>(rois, feat, strd, N, B, C, H, W, out);
}

// Round 2
// 22.702 us; speedup vs baseline: 1.3471x; 1.3471x over previous
//
#include <hip/hip_runtime.h>
#include <hip/hip_bf16.h>

// PSRoIAlign: features [B, C=D*G*G, H, W] fp32, rois [N,5] (b, x1,y1,x2,y2 in
// image coords), output [N, D, G, G] fp32. G=7, SR=2, D=10 for this problem.
//
// Round 2: one thread per (output, sample). 4 lanes = one output's 2x2 sample
// grid; reduce with __shfl_xor. 4x wave count vs round 1 to hide gather latency.

#define G 7
#define SR 2
#define D_OUT 10

__global__ void psroi_align_kernel(const float* __restrict__ rois,
                                   const float* __restrict__ feat,
                                   const int* __restrict__ stride_p,
                                   int N, int B, int C, int H, int W,
                                   float* __restrict__ out) {
    int idx = blockIdx.x * blockDim.x + threadIdx.x;
    int total = N * D_OUT * G * G * (SR * SR);
    if (idx >= total) return;

    int s       = idx & 3;        // sample id: iy = s>>1, ix = s&1
    int out_idx = idx >> 2;
    int iy = s >> 1;
    int ix = s & 1;

    // stride may arrive as int32 or float32 bits; disambiguate.
    int iv = stride_p[0];
    float stride_f;
    if (iv > 0 && iv <= 65536) stride_f = (float)iv;
    else                       stride_f = __int_as_float(iv);
    float spatial_scale = 1.0f / stride_f;

    int pw = out_idx % G;
    int ph = (out_idx / G) % G;
    int d  = (out_idx / (G * G)) % D_OUT;
    int n  = out_idx / (G * G * D_OUT);

    const float* roi = rois + (size_t)n * 5;
    int   b  = (int)roi[0];
    float sw = roi[1] * spatial_scale - 0.5f;
    float sh = roi[2] * spatial_scale - 0.5f;
    float ew = roi[3] * spatial_scale - 0.5f;
    float eh = roi[4] * spatial_scale - 0.5f;
    float roi_w = fmaxf(ew - sw, 0.1f);
    float roi_h = fmaxf(eh - sh, 0.1f);
    float bin_h = roi_h / (float)G;
    float bin_w = roi_w / (float)G;

    // position-sensitive channel: c = (d*G + ph)*G + pw
    int c = (d * G + ph) * G + pw;
    const float* __restrict__ fplane = feat + ((size_t)b * C + c) * (size_t)(H * W);

    // this thread's single bilinear sample
    float y  = sh + ((float)ph + ((float)iy + 0.5f) / (float)SR) * bin_h;
    float x  = sw + ((float)pw + ((float)ix + 0.5f) / (float)SR) * bin_w;
    bool  vy = (y > -1.0f) && (y < (float)H);
    bool  vx = (x > -1.0f) && (x < (float)W);

    float cy = fmaxf(y, 0.0f);
    int  ylo = min((int)floorf(cy), H - 1);
    int  yhi = min(ylo + 1, H - 1);
    float ly = (ylo >= H - 1) ? 0.0f : (cy - (float)ylo);
    float hy = 1.0f - ly;

    float cx = fmaxf(x, 0.0f);
    int  xlo = min((int)floorf(cx), W - 1);
    int  xhi = min(xlo + 1, W - 1);
    float lx = (xlo >= W - 1) ? 0.0f : (cx - (float)xlo);
    float hx = 1.0f - lx;

    float val = 0.0f;
    if (vy && vx) {
        float v00 = fplane[(size_t)ylo * W + xlo];
        float v01 = fplane[(size_t)ylo * W + xhi];
        float v10 = fplane[(size_t)yhi * W + xlo];
        float v11 = fplane[(size_t)yhi * W + xhi];
        val = hy * hx * v00 + hy * lx * v01 + ly * hx * v10 + ly * lx * v11;
    }

    // reduce the 2x2 sample grid across the 4-lane group
    val += __shfl_xor(val, 1);
    val += __shfl_xor(val, 2);
    if (s == 0) out[out_idx] = val * (1.0f / (float)(SR * SR));
}

extern "C" void kernel_launch(void* const* d_in, const int* in_sizes, int n_in,
                              void* d_out, int out_size, void* d_ws, size_t ws_size,
                              hipStream_t stream) {
    const float* rois = (const float*)d_in[0];
    const float* feat = (const float*)d_in[1];
    const int*   strd = (const int*)d_in[2];
    float* out = (float*)d_out;

    int N = in_sizes[0] / 5;
    const int C = D_OUT * G * G;   // 490
    const int H = 160, W = 160;
    int B = in_sizes[1] / (C * H * W);

    int total = N * D_OUT * G * G * (SR * SR);
    int block = 256;
    int grid = (total + block - 1) / block;
    psroi_align_kernel<<<grid, block, 0, stream>>>(rois, feat, strd, N, B, C, H, W, out);
}